// Round 1
// baseline (441.519 us; speedup 1.0000x reference)
//
#include <hip/hip_runtime.h>

#ifndef __has_builtin
#define __has_builtin(x) 0
#endif

#define NOBS_OS 8
#define NOBS_TS 6
#define HID 128
#define NACT 9
#define BTOT 32768
#define NTS 32
#define ROWS 16     // batch rows per tile
#define TILES 4     // tiles per block
#define NBLOCKS 512 // 512*4*16 = 32768

typedef __attribute__((ext_vector_type(8))) short short8;
typedef __attribute__((ext_vector_type(4))) float f32x4;

__device__ inline unsigned short f2bf(float x) {
  // round-to-nearest-even f32 -> bf16 bits (inputs never NaN here)
  unsigned int u = __float_as_uint(x);
  u += 0x7FFFu + ((u >> 16) & 1u);
  return (unsigned short)(u >> 16);
}

__device__ inline float fexp2(float x) {
#if __has_builtin(__builtin_amdgcn_exp2f)
  return __builtin_amdgcn_exp2f(x);
#else
  return exp2f(x);
#endif
}
__device__ inline float frcp_(float x) {
#if __has_builtin(__builtin_amdgcn_rcpf)
  return __builtin_amdgcn_rcpf(x);
#else
  return 1.0f / x;
#endif
}
__device__ inline float fsigmoid(float x) {
  return frcp_(1.0f + fexp2(x * -1.44269504088896340736f));
}
__device__ inline float ftanh_(float x) {
  float e = fexp2(x * -2.88539008177792681472f); // exp(-2x)
  return (1.0f - e) * frcp_(1.0f + e);
}

__device__ inline short8 pack8(f32x4 a, f32x4 b) {
  short8 r;
  r[0] = (short)f2bf(a[0]); r[1] = (short)f2bf(a[1]);
  r[2] = (short)f2bf(a[2]); r[3] = (short)f2bf(a[3]);
  r[4] = (short)f2bf(b[0]); r[5] = (short)f2bf(b[1]);
  r[6] = (short)f2bf(b[2]); r[7] = (short)f2bf(b[3]);
  return r;
}

// A-frag layout in LDS (16 rows x K): elem idx = kt*512 + lane*8 + jj
// (lane = q*16+c reads A[m=c][k=32*kt+8*q+jj] as ds_read_b128)
// writes from C-layout use: idx = kt*512 + qa*128 + m*8 + jj with
// qa=(k>>3)&3, jj=k&7, m=q*4+r.

__global__ __launch_bounds__(256, 2) void recdqn_kernel(
    const float* __restrict__ s, const float* __restrict__ W_os,
    const float* __restrict__ b_os, const float* __restrict__ W_ih,
    const float* __restrict__ W_hh, const float* __restrict__ b_ih,
    const float* __restrict__ b_hh, const float* __restrict__ W_ts,
    const float* __restrict__ b_ts, const float* __restrict__ W_c1,
    const float* __restrict__ b_c1, const float* __restrict__ W_c2,
    const float* __restrict__ b_c2, float* __restrict__ out) {
  __shared__ unsigned short x_st[ROWS * 264]; // [row][t][8] bf16, row stride 264 (bank stagger)
  __shared__ unsigned short hA[2][2048];      // h in A-frag layout, double buffered (K=128)
  __shared__ unsigned short xcat[4096];       // concat(x_OS, x_TS) A-frag layout (K=256)
  __shared__ unsigned short x2[2048];         // W_c1 output A-frag layout (K=128)
  __shared__ int n_lds[ROWS];
  __shared__ int tmax_s;

  const int tid = threadIdx.x;
  const int lane = tid & 63;
  const int w = tid >> 6;   // wave 0..3: owns hidden slice [32w, 32w+32)
  const int c = lane & 15;
  const int q = lane >> 4;

  const short8 z8 = {0, 0, 0, 0, 0, 0, 0, 0};

  // ---- one-time: W_hh/W_ih B-fragments (bf16) + combined bias, register-resident.
  // acc slot a = gate*2 + u, gate in {i,f,g,o}, u in {0,1}; col n = gate*128 + 32w + 16u + c
  short8 Bh[8][5];
  float bias_a[8];
#pragma unroll
  for (int a = 0; a < 8; ++a) {
    const int n = ((a >> 1) << 7) + (w << 5) + ((a & 1) << 4) + c;
    bias_a[a] = b_ih[n] + b_hh[n];
#pragma unroll
    for (int kt = 0; kt < 4; ++kt) {
      const f32x4* p = (const f32x4*)(W_hh + n * HID + kt * 32 + q * 8);
      Bh[a][kt] = pack8(p[0], p[1]);
    }
    short8 fx = z8;
    if (q == 0) { // k = 128 + jj : W_ih rows (jj<6), zero-padded
      const float* px = W_ih + n * NOBS_TS;
      fx[0] = (short)f2bf(px[0]); fx[1] = (short)f2bf(px[1]);
      fx[2] = (short)f2bf(px[2]); fx[3] = (short)f2bf(px[3]);
      fx[4] = (short)f2bf(px[4]); fx[5] = (short)f2bf(px[5]);
    }
    Bh[a][4] = fx;
  }

  // write base for C-layout -> A-frag-layout (k = j = 32w+16u+c, m = q*4+r):
  // idx = w*512 + (c>>3)*128 + q*32 + (c&7)  [+ u*256 + r*8]
  const int pbase = w * 512 + ((c >> 3) << 7) + (q << 5) + (c & 7);

  for (int tile = 0; tile < TILES; ++tile) {
    const int b0 = (blockIdx.x * TILES + tile) * ROWS;
    __syncthreads(); // protect LDS reuse across tiles

    // ---- stage s_TS -> LDS bf16 (NaN->0), count n_obs
    for (int i = tid; i < ROWS * 264; i += 256) x_st[i] = 0;
    if (tid < ROWS) n_lds[tid] = 0;
    __syncthreads();
    for (int p = tid; p < ROWS * NTS; p += 256) {
      const int r = p >> 5, t = p & 31;
      const float* src = s + (size_t)(b0 + r) * 200 + 8 + t * 6;
      const float v0 = src[0];
      if (!(v0 != v0)) atomicAdd(&n_lds[r], 1);
#pragma unroll
      for (int e = 0; e < 6; ++e) {
        float v = src[e];
        v = (v != v) ? 0.0f : v;
        x_st[r * 264 + t * 8 + e] = f2bf(v);
      }
    }
    __syncthreads();
    if (tid == 0) {
      int m = 0;
      for (int r = 0; r < ROWS; ++r) m = max(m, n_lds[r]);
      tmax_s = m;
    }
    __syncthreads();
    const int tmax = tmax_s;
    int tcap[4];
#pragma unroll
    for (int r = 0; r < 4; ++r) tcap[r] = n_lds[q * 4 + r] - 1;

    float cc[8], xts[8];
#pragma unroll
    for (int i = 0; i < 8; ++i) { cc[i] = 0.0f; xts[i] = 0.0f; }

    // ---- LSTM time loop (runs only to tile max length)
    for (int t = 0; t < tmax; ++t) {
      f32x4 acc[8];
#pragma unroll
      for (int a = 0; a < 8; ++a) {
        const float bb = bias_a[a];
        f32x4 bv = {bb, bb, bb, bb};
        acc[a] = bv;
      }
      // x-gate part (K-tile 4)
      short8 ax = z8;
      if (q == 0) ax = *(const short8*)&x_st[c * 264 + t * 8];
#pragma unroll
      for (int a = 0; a < 8; ++a)
        acc[a] = __builtin_amdgcn_mfma_f32_16x16x32_bf16(ax, Bh[a][4], acc[a], 0, 0, 0);
      // h part (K-tiles 0..3); h == 0 at t == 0
      if (t > 0) {
        const unsigned short* hb = hA[(t + 1) & 1];
#pragma unroll
        for (int kt = 0; kt < 4; ++kt) {
          const short8 ah = *(const short8*)&hb[kt * 512 + lane * 8];
#pragma unroll
          for (int a = 0; a < 8; ++a)
            acc[a] = __builtin_amdgcn_mfma_f32_16x16x32_bf16(ah, Bh[a][kt], acc[a], 0, 0, 0);
        }
      }
      // activations + state update; write new h (bf16) into other buffer
      unsigned short* hw = &hA[t & 1][pbase];
#pragma unroll
      for (int u = 0; u < 2; ++u) {
#pragma unroll
        for (int r = 0; r < 4; ++r) {
          const float iv = fsigmoid(acc[0 + u][r]);
          const float fv = fsigmoid(acc[2 + u][r]);
          const float gv = ftanh_(acc[4 + u][r]);
          const float ov = fsigmoid(acc[6 + u][r]);
          const int ui = u * 4 + r;
          const float cv = fv * cc[ui] + iv * gv;
          cc[ui] = cv;
          const float hv = ov * ftanh_(cv);
          if (t == tcap[r]) xts[ui] = hv; // capture f32 h at t == n_obs-1
          hw[u * 256 + r * 8] = f2bf(hv);
        }
      }
      __syncthreads();
    }

    // ---- x_TS raw -> hA[0] in A-frag layout (zeros if n_obs==0)
    {
      unsigned short* pw = &hA[0][pbase];
#pragma unroll
      for (int u = 0; u < 2; ++u)
#pragma unroll
        for (int r = 0; r < 4; ++r) pw[u * 256 + r * 8] = f2bf(xts[u * 4 + r]);
    }
    __syncthreads();

    // ---- x_TS = relu(x_TS @ W_ts^T + b_ts) -> xcat k=128+j
    {
      f32x4 acc2[2];
#pragma unroll
      for (int u = 0; u < 2; ++u) {
        const float bb = b_ts[(w << 5) + (u << 4) + c];
        f32x4 bv = {bb, bb, bb, bb};
        acc2[u] = bv;
      }
#pragma unroll
      for (int kt = 0; kt < 4; ++kt) {
        const short8 af = *(const short8*)&hA[0][kt * 512 + lane * 8];
#pragma unroll
        for (int u = 0; u < 2; ++u) {
          const int n = (w << 5) + (u << 4) + c;
          const f32x4* p = (const f32x4*)(W_ts + n * HID + kt * 32 + q * 8);
          acc2[u] = __builtin_amdgcn_mfma_f32_16x16x32_bf16(af, pack8(p[0], p[1]), acc2[u], 0, 0, 0);
        }
      }
      unsigned short* pw = &xcat[2048 + pbase];
#pragma unroll
      for (int u = 0; u < 2; ++u)
#pragma unroll
        for (int r = 0; r < 4; ++r)
          pw[u * 256 + r * 8] = f2bf(fmaxf(acc2[u][r], 0.0f));
    }

    // ---- x_OS = relu(s_OS @ W_os^T + b_os) -> xcat k=j
    {
      short8 aos = z8;
      if (q == 0) {
        const f32x4* p = (const f32x4*)(s + (size_t)(b0 + c) * 200);
        aos = pack8(p[0], p[1]);
      }
      f32x4 acc2[2];
#pragma unroll
      for (int u = 0; u < 2; ++u) {
        const int n = (w << 5) + (u << 4) + c;
        const float bb = b_os[n];
        f32x4 bv = {bb, bb, bb, bb};
        acc2[u] = bv;
        short8 bf = z8;
        if (q == 0) {
          const f32x4* p = (const f32x4*)(W_os + n * NOBS_OS);
          bf = pack8(p[0], p[1]);
        }
        acc2[u] = __builtin_amdgcn_mfma_f32_16x16x32_bf16(aos, bf, acc2[u], 0, 0, 0);
      }
      unsigned short* pw = &xcat[pbase];
#pragma unroll
      for (int u = 0; u < 2; ++u)
#pragma unroll
        for (int r = 0; r < 4; ++r)
          pw[u * 256 + r * 8] = f2bf(fmaxf(acc2[u][r], 0.0f));
    }
    __syncthreads();

    // ---- x = relu(xcat @ W_c1^T + b_c1) -> x2 (K=256)
    {
      f32x4 acc2[2];
#pragma unroll
      for (int u = 0; u < 2; ++u) {
        const float bb = b_c1[(w << 5) + (u << 4) + c];
        f32x4 bv = {bb, bb, bb, bb};
        acc2[u] = bv;
      }
#pragma unroll
      for (int kt = 0; kt < 8; ++kt) {
        const short8 af = *(const short8*)&xcat[kt * 512 + lane * 8];
#pragma unroll
        for (int u = 0; u < 2; ++u) {
          const int n = (w << 5) + (u << 4) + c;
          const f32x4* p = (const f32x4*)(W_c1 + n * 256 + kt * 32 + q * 8);
          acc2[u] = __builtin_amdgcn_mfma_f32_16x16x32_bf16(af, pack8(p[0], p[1]), acc2[u], 0, 0, 0);
        }
      }
      unsigned short* pw = &x2[pbase];
#pragma unroll
      for (int u = 0; u < 2; ++u)
#pragma unroll
        for (int r = 0; r < 4; ++r)
          pw[u * 256 + r * 8] = f2bf(fmaxf(acc2[u][r], 0.0f));
    }
    __syncthreads();

    // ---- out = x2 @ W_c2^T + b_c2 (wave 0 only; cols c<9 valid)
    if (w == 0) {
      const float bb = (c < NACT) ? b_c2[c] : 0.0f;
      f32x4 accf = {bb, bb, bb, bb};
#pragma unroll
      for (int kt = 0; kt < 4; ++kt) {
        const short8 af = *(const short8*)&x2[kt * 512 + lane * 8];
        short8 bf = z8;
        if (c < NACT) {
          const f32x4* p = (const f32x4*)(W_c2 + c * HID + kt * 32 + q * 8);
          bf = pack8(p[0], p[1]);
        }
        accf = __builtin_amdgcn_mfma_f32_16x16x32_bf16(af, bf, accf, 0, 0, 0);
      }
      if (c < NACT) {
#pragma unroll
        for (int r = 0; r < 4; ++r)
          out[(size_t)(b0 + q * 4 + r) * NACT + c] = accf[r];
      }
    }
  }
}

extern "C" void kernel_launch(void* const* d_in, const int* in_sizes, int n_in,
                              void* d_out, int out_size, void* d_ws, size_t ws_size,
                              hipStream_t stream) {
  (void)in_sizes; (void)n_in; (void)out_size; (void)d_ws; (void)ws_size;
  const float* s    = (const float*)d_in[0];
  const float* W_os = (const float*)d_in[1];
  const float* b_os = (const float*)d_in[2];
  const float* W_ih = (const float*)d_in[3];
  const float* W_hh = (const float*)d_in[4];
  const float* b_ih = (const float*)d_in[5];
  const float* b_hh = (const float*)d_in[6];
  const float* W_ts = (const float*)d_in[7];
  const float* b_ts = (const float*)d_in[8];
  const float* W_c1 = (const float*)d_in[9];
  const float* b_c1 = (const float*)d_in[10];
  const float* W_c2 = (const float*)d_in[11];
  const float* b_c2 = (const float*)d_in[12];
  float* outp = (float*)d_out;

  recdqn_kernel<<<NBLOCKS, 256, 0, stream>>>(s, W_os, b_os, W_ih, W_hh, b_ih,
                                             b_hh, W_ts, b_ts, W_c1, b_c1,
                                             W_c2, b_c2, outp);
}

// Round 2
// 363.662 us; speedup vs baseline: 1.2141x; 1.2141x over previous
//
#include <hip/hip_runtime.h>

#ifndef __has_builtin
#define __has_builtin(x) 0
#endif

#define NOBS_OS 8
#define NOBS_TS 6
#define HID 128
#define NACT 9
#define BTOT 32768
#define NTS 32
#define ROWS 16     // batch rows per tile
#define TILES 4     // tiles per block
#define NBLOCKS 512 // 512*4*16 = 32768
#define BLOCK 512   // 8 waves; wave w owns hidden cols [16w,16w+16)

typedef __attribute__((ext_vector_type(8))) short short8;
typedef __attribute__((ext_vector_type(4))) float f32x4;

__device__ inline unsigned short f2bf(float x) {
  unsigned int u = __float_as_uint(x);
  u += 0x7FFFu + ((u >> 16) & 1u);
  return (unsigned short)(u >> 16);
}

__device__ inline float fexp2(float x) {
#if __has_builtin(__builtin_amdgcn_exp2f)
  return __builtin_amdgcn_exp2f(x);
#else
  return exp2f(x);
#endif
}
__device__ inline float frcp_(float x) {
#if __has_builtin(__builtin_amdgcn_rcpf)
  return __builtin_amdgcn_rcpf(x);
#else
  return 1.0f / x;
#endif
}
__device__ inline float fsigmoid(float x) {
  return frcp_(1.0f + fexp2(x * -1.44269504088896340736f));
}
__device__ inline float ftanh_(float x) {
  float e = fexp2(x * -2.88539008177792681472f); // exp(-2x)
  return (1.0f - e) * frcp_(1.0f + e);
}

__device__ inline short8 pack8(f32x4 a, f32x4 b) {
  short8 r;
  r[0] = (short)f2bf(a[0]); r[1] = (short)f2bf(a[1]);
  r[2] = (short)f2bf(a[2]); r[3] = (short)f2bf(a[3]);
  r[4] = (short)f2bf(b[0]); r[5] = (short)f2bf(b[1]);
  r[6] = (short)f2bf(b[2]); r[7] = (short)f2bf(b[3]);
  return r;
}

// A-frag layout in LDS (16 rows x K): elem idx = kt*512 + lane*8 + jj
// (lane = q*16+c reads A[m=c][k=32*kt+8*q+jj] as ds_read_b128)
// C-layout writes at column k use: idx = (k>>5)*512 + ((k>>3)&3)*128 + m*8 + (k&7),
// m = q*4+r.

__global__ __launch_bounds__(BLOCK, 2) void recdqn_kernel(
    const float* __restrict__ s, const float* __restrict__ W_os,
    const float* __restrict__ b_os, const float* __restrict__ W_ih,
    const float* __restrict__ W_hh, const float* __restrict__ b_ih,
    const float* __restrict__ b_hh, const float* __restrict__ W_ts,
    const float* __restrict__ b_ts, const float* __restrict__ W_c1,
    const float* __restrict__ b_c1, const float* __restrict__ W_c2,
    const float* __restrict__ b_c2, float* __restrict__ out) {
  __shared__ unsigned short x_st[ROWS * 264]; // [row][t][8] bf16
  __shared__ unsigned short hA[2][2048];      // h in A-frag layout, double buffered
  __shared__ unsigned short xcat[4096];       // concat(x_OS, x_TS) A-frag layout (K=256)
  __shared__ unsigned short x2[2048];         // W_c1 output A-frag layout (K=128)
  __shared__ int n_lds[ROWS];
  __shared__ int tmax_s;

  const int tid = threadIdx.x;
  const int lane = tid & 63;
  const int w = tid >> 6;   // wave 0..7: hidden cols [16w, 16w+16)
  const int c = lane & 15;
  const int q = lane >> 4;
  const int j = (w << 4) | c; // this lane's hidden/output column

  const short8 z8 = {0, 0, 0, 0, 0, 0, 0, 0};

  // ---- one-time: W_hh/W_ih B-fragments (bf16) + combined bias, register-resident.
  // gate a in {i,f,g,o}: col n = a*128 + j. 20 frags = 80 VGPRs.
  short8 Bh[4][5];
  float bias_a[4];
#pragma unroll
  for (int a = 0; a < 4; ++a) {
    const int n = (a << 7) + j;
    bias_a[a] = b_ih[n] + b_hh[n];
#pragma unroll
    for (int kt = 0; kt < 4; ++kt) {
      const f32x4* p = (const f32x4*)(W_hh + n * HID + kt * 32 + q * 8);
      Bh[a][kt] = pack8(p[0], p[1]);
    }
    short8 fx = z8;
    if (q == 0) { // k = 128 + jj : W_ih rows (jj<6), zero-padded
      const float* px = W_ih + n * NOBS_TS;
      fx[0] = (short)f2bf(px[0]); fx[1] = (short)f2bf(px[1]);
      fx[2] = (short)f2bf(px[2]); fx[3] = (short)f2bf(px[3]);
      fx[4] = (short)f2bf(px[4]); fx[5] = (short)f2bf(px[5]);
    }
    Bh[a][4] = fx;
  }

  // C-layout -> A-frag-layout write base for column j, rows m = q*4 + r
  const int pbase = ((j >> 5) << 9) + (((j >> 3) & 3) << 7) + (q << 5) + (j & 7);

  for (int tile = 0; tile < TILES; ++tile) {
    const int b0 = (blockIdx.x * TILES + tile) * ROWS;
    __syncthreads(); // protect LDS reuse across tiles

    // ---- stage s_TS -> LDS bf16 (NaN->0), count n_obs
    for (int i = tid; i < ROWS * 264; i += BLOCK) x_st[i] = 0;
    if (tid < ROWS) n_lds[tid] = 0;
    __syncthreads();
    {
      const int r = tid >> 5, t = tid & 31; // 512 threads == ROWS*NTS slots
      const float* src = s + (size_t)(b0 + r) * 200 + 8 + t * 6;
      const float v0 = src[0];
      if (!(v0 != v0)) atomicAdd(&n_lds[r], 1);
#pragma unroll
      for (int e = 0; e < 6; ++e) {
        float v = src[e];
        v = (v != v) ? 0.0f : v;
        x_st[r * 264 + t * 8 + e] = f2bf(v);
      }
    }
    __syncthreads();
    if (tid == 0) {
      int m = 0;
      for (int r = 0; r < ROWS; ++r) m = max(m, n_lds[r]);
      tmax_s = m;
    }
    __syncthreads();
    const int tmax = tmax_s;
    int tcap[4];
#pragma unroll
    for (int r = 0; r < 4; ++r) tcap[r] = n_lds[q * 4 + r] - 1;

    float cc[4], xts[4];
#pragma unroll
    for (int i = 0; i < 4; ++i) { cc[i] = 0.0f; xts[i] = 0.0f; }

    // ---- LSTM time loop (runs only to tile max length)
    for (int t = 0; t < tmax; ++t) {
      f32x4 acc[4];
#pragma unroll
      for (int a = 0; a < 4; ++a) {
        const float bb = bias_a[a];
        f32x4 bv = {bb, bb, bb, bb};
        acc[a] = bv;
      }
      // x-gate part (K-tile 4)
      short8 ax = z8;
      if (q == 0) ax = *(const short8*)&x_st[c * 264 + t * 8];
#pragma unroll
      for (int a = 0; a < 4; ++a)
        acc[a] = __builtin_amdgcn_mfma_f32_16x16x32_bf16(ax, Bh[a][4], acc[a], 0, 0, 0);
      // h part (K-tiles 0..3); h == 0 at t == 0
      if (t > 0) {
        const unsigned short* hb = hA[(t + 1) & 1];
#pragma unroll
        for (int kt = 0; kt < 4; ++kt) {
          const short8 ah = *(const short8*)&hb[kt * 512 + lane * 8];
#pragma unroll
          for (int a = 0; a < 4; ++a)
            acc[a] = __builtin_amdgcn_mfma_f32_16x16x32_bf16(ah, Bh[a][kt], acc[a], 0, 0, 0);
        }
      }
      // activations + state update; write new h (bf16) into other buffer
      unsigned short* hw = &hA[t & 1][pbase];
#pragma unroll
      for (int r = 0; r < 4; ++r) {
        const float iv = fsigmoid(acc[0][r]);
        const float fv = fsigmoid(acc[1][r]);
        const float gv = ftanh_(acc[2][r]);
        const float ov = fsigmoid(acc[3][r]);
        const float cv = fv * cc[r] + iv * gv;
        cc[r] = cv;
        const float hv = ov * ftanh_(cv);
        if (t == tcap[r]) xts[r] = hv; // capture f32 h at t == n_obs-1
        hw[r * 8] = f2bf(hv);
      }
      __syncthreads();
    }

    // ---- x_TS raw -> hA[0] in A-frag layout (zeros if n_obs==0)
    {
      unsigned short* pw = &hA[0][pbase];
#pragma unroll
      for (int r = 0; r < 4; ++r) pw[r * 8] = f2bf(xts[r]);
    }
    __syncthreads();

    // ---- x_TS = relu(x_TS @ W_ts^T + b_ts) -> xcat k=128+j
    {
      const float bb = b_ts[j];
      f32x4 acc2 = {bb, bb, bb, bb};
#pragma unroll
      for (int kt = 0; kt < 4; ++kt) {
        const short8 af = *(const short8*)&hA[0][kt * 512 + lane * 8];
        const f32x4* p = (const f32x4*)(W_ts + j * HID + kt * 32 + q * 8);
        acc2 = __builtin_amdgcn_mfma_f32_16x16x32_bf16(af, pack8(p[0], p[1]), acc2, 0, 0, 0);
      }
      unsigned short* pw = &xcat[2048 + pbase];
#pragma unroll
      for (int r = 0; r < 4; ++r) pw[r * 8] = f2bf(fmaxf(acc2[r], 0.0f));
    }

    // ---- x_OS = relu(s_OS @ W_os^T + b_os) -> xcat k=j
    {
      short8 aos = z8;
      if (q == 0) {
        const f32x4* p = (const f32x4*)(s + (size_t)(b0 + c) * 200);
        aos = pack8(p[0], p[1]);
      }
      const float bb = b_os[j];
      f32x4 acc2 = {bb, bb, bb, bb};
      short8 bf = z8;
      if (q == 0) {
        const f32x4* p = (const f32x4*)(W_os + j * NOBS_OS);
        bf = pack8(p[0], p[1]);
      }
      acc2 = __builtin_amdgcn_mfma_f32_16x16x32_bf16(aos, bf, acc2, 0, 0, 0);
      unsigned short* pw = &xcat[pbase];
#pragma unroll
      for (int r = 0; r < 4; ++r) pw[r * 8] = f2bf(fmaxf(acc2[r], 0.0f));
    }
    __syncthreads();

    // ---- x = relu(xcat @ W_c1^T + b_c1) -> x2 (K=256)
    {
      const float bb = b_c1[j];
      f32x4 acc2 = {bb, bb, bb, bb};
#pragma unroll
      for (int kt = 0; kt < 8; ++kt) {
        const short8 af = *(const short8*)&xcat[kt * 512 + lane * 8];
        const f32x4* p = (const f32x4*)(W_c1 + j * 256 + kt * 32 + q * 8);
        acc2 = __builtin_amdgcn_mfma_f32_16x16x32_bf16(af, pack8(p[0], p[1]), acc2, 0, 0, 0);
      }
      unsigned short* pw = &x2[pbase];
#pragma unroll
      for (int r = 0; r < 4; ++r) pw[r * 8] = f2bf(fmaxf(acc2[r], 0.0f));
    }
    __syncthreads();

    // ---- out = x2 @ W_c2^T + b_c2 (wave 0 only; cols c<9 valid)
    if (w == 0) {
      const float bb = (c < NACT) ? b_c2[c] : 0.0f;
      f32x4 accf = {bb, bb, bb, bb};
#pragma unroll
      for (int kt = 0; kt < 4; ++kt) {
        const short8 af = *(const short8*)&x2[kt * 512 + lane * 8];
        short8 bf = z8;
        if (c < NACT) {
          const f32x4* p = (const f32x4*)(W_c2 + c * HID + kt * 32 + q * 8);
          bf = pack8(p[0], p[1]);
        }
        accf = __builtin_amdgcn_mfma_f32_16x16x32_bf16(af, bf, accf, 0, 0, 0);
      }
      if (c < NACT) {
#pragma unroll
        for (int r = 0; r < 4; ++r)
          out[(size_t)(b0 + q * 4 + r) * NACT + c] = accf[r];
      }
    }
  }
}

extern "C" void kernel_launch(void* const* d_in, const int* in_sizes, int n_in,
                              void* d_out, int out_size, void* d_ws, size_t ws_size,
                              hipStream_t stream) {
  (void)in_sizes; (void)n_in; (void)out_size; (void)d_ws; (void)ws_size;
  const float* s    = (const float*)d_in[0];
  const float* W_os = (const float*)d_in[1];
  const float* b_os = (const float*)d_in[2];
  const float* W_ih = (const float*)d_in[3];
  const float* W_hh = (const float*)d_in[4];
  const float* b_ih = (const float*)d_in[5];
  const float* b_hh = (const float*)d_in[6];
  const float* W_ts = (const float*)d_in[7];
  const float* b_ts = (const float*)d_in[8];
  const float* W_c1 = (const float*)d_in[9];
  const float* b_c1 = (const float*)d_in[10];
  const float* W_c2 = (const float*)d_in[11];
  const float* b_c2 = (const float*)d_in[12];
  float* outp = (float*)d_out;

  recdqn_kernel<<<NBLOCKS, BLOCK, 0, stream>>>(s, W_os, b_os, W_ih, W_hh, b_ih,
                                               b_hh, W_ts, b_ts, W_c1, b_c1,
                                               W_c2, b_c2, outp);
}